// Round 5
// baseline (58.007 us; speedup 1.0000x reference)
//
#include <hip/hip_runtime.h>

// PCEN [B=64,C=128,T=4000] f32: M_t = 0.975 M_{t-1} + 0.025 x_t (M_{-1}=0);
//   y = sqrt(x * (M+1e-6)^-0.98 + 2) - sqrt(2)
// R5: wave-parallel affine scan, 8 elems/lane (tile=512) -- halves the number of
// serial scan chains per row (8 vs 16). Exclusive carry via E=(I-b)/K (1 VALU op)
// instead of an extra serial shfl. One wave per row, exact, no LDS.

#define T_LEN 4000
#define EPL   8                       // elements per lane
#define TILE  (64 * EPL)              // 512
#define NFULL (T_LEN / TILE)          // 7 full tiles (3584)
#define TAILL ((T_LEN - NFULL*TILE) / EPL)  // 52 active lanes in 416-elem tail

constexpr double dpow(double b, int e) { double r = 1.0; for (int i = 0; i < e; ++i) r *= b; return r; }

__device__ __forceinline__ float pcen_y(float x, float M) {
    float p = __builtin_amdgcn_exp2f(-0.98f * __builtin_amdgcn_logf(M + 1e-6f));
    return sqrtf(fmaf(x, p, 2.0f)) - 1.41421356237309515f;
}

__global__ __launch_bounds__(256) void pcen_kernel(const float* __restrict__ x,
                                                   float* __restrict__ y) {
    const int wid  = threadIdx.x >> 6;
    const int lane = threadIdx.x & 63;
    const int row  = blockIdx.x * 4 + wid;

    const float S = 0.025f, OMS = 0.975f;
    // K = 0.975^EPL; scan-step multipliers K^d
    const float K1   = (float)dpow(0.975, EPL);
    const float K2   = (float)dpow(0.975, EPL * 2);
    const float K4   = (float)dpow(0.975, EPL * 4);
    const float K8   = (float)dpow(0.975, EPL * 8);
    const float K16  = (float)dpow(0.975, EPL * 16);
    const float K32  = (float)dpow(0.975, EPL * 32);
    const float KT   = (float)dpow(0.975, TILE);      // whole-tile decay
    const float invK = (float)(1.0 / dpow(0.975, EPL));

    // c = 0.975^(EPL*lane): decay across lanes below this one
    const float c = __builtin_amdgcn_exp2f((float)lane * (EPL * -0.036525699374527566f));

    const float* __restrict__ xr = x + (size_t)row * T_LEN;
    float*       __restrict__ yr = y + (size_t)row * T_LEN;

    float M0 = 0.0f;
    // prefetch tile 0 (two float4 = lane's 8 consecutive elements)
    float4 va = *reinterpret_cast<const float4*>(xr + lane * EPL);
    float4 vb = *reinterpret_cast<const float4*>(xr + lane * EPL + 4);

    for (int t = 0; t < NFULL; ++t) {
        const float4 a = va, b4 = vb;
        if (t + 1 < NFULL) {
            va = *reinterpret_cast<const float4*>(xr + (t + 1) * TILE + lane * EPL);
            vb = *reinterpret_cast<const float4*>(xr + (t + 1) * TILE + lane * EPL + 4);
        }

        // local affine offset over this lane's 8 elements (from M=0)
        float b = S * a.x;
        b = fmaf(S, a.y,  OMS * b);
        b = fmaf(S, a.z,  OMS * b);
        b = fmaf(S, a.w,  OMS * b);
        b = fmaf(S, b4.x, OMS * b);
        b = fmaf(S, b4.y, OMS * b);
        b = fmaf(S, b4.z, OMS * b);
        b = fmaf(S, b4.w, OMS * b);

        // inclusive geometric scan over lanes, K = 0.975^8
        float I = b, tv;
        tv = __shfl_up(I, 1);  I = fmaf(K1,  (lane >= 1  ? tv : 0.0f), I);
        tv = __shfl_up(I, 2);  I = fmaf(K2,  (lane >= 2  ? tv : 0.0f), I);
        tv = __shfl_up(I, 4);  I = fmaf(K4,  (lane >= 4  ? tv : 0.0f), I);
        tv = __shfl_up(I, 8);  I = fmaf(K8,  (lane >= 8  ? tv : 0.0f), I);
        tv = __shfl_up(I, 16); I = fmaf(K16, (lane >= 16 ? tv : 0.0f), I);
        tv = __shfl_up(I, 32); I = fmaf(K32, (lane >= 32 ? tv : 0.0f), I);

        // exclusive carry-in: E = (I - b)/K  (avoids a serial shfl)
        float M = fmaf(c, M0, (I - b) * invK);

        float4 oa, ob;
        M = fmaf(S, a.x,  OMS * M);  oa.x = pcen_y(a.x,  M);
        M = fmaf(S, a.y,  OMS * M);  oa.y = pcen_y(a.y,  M);
        M = fmaf(S, a.z,  OMS * M);  oa.z = pcen_y(a.z,  M);
        M = fmaf(S, a.w,  OMS * M);  oa.w = pcen_y(a.w,  M);
        M = fmaf(S, b4.x, OMS * M);  ob.x = pcen_y(b4.x, M);
        M = fmaf(S, b4.y, OMS * M);  ob.y = pcen_y(b4.y, M);
        M = fmaf(S, b4.z, OMS * M);  ob.z = pcen_y(b4.z, M);
        M = fmaf(S, b4.w, OMS * M);  ob.w = pcen_y(b4.w, M);

        *reinterpret_cast<float4*>(yr + t * TILE + lane * EPL)     = oa;
        *reinterpret_cast<float4*>(yr + t * TILE + lane * EPL + 4) = ob;

        // cross-tile carry
        const float Ilast = __shfl(I, 63);
        M0 = fmaf(KT, M0, Ilast);
    }

    // tail: 416 elements, lanes 0..51 active
    {
        const bool act = lane < TAILL;
        float4 a  = make_float4(0.f, 0.f, 0.f, 0.f);
        float4 b4 = make_float4(0.f, 0.f, 0.f, 0.f);
        if (act) {
            a  = *reinterpret_cast<const float4*>(xr + NFULL * TILE + lane * EPL);
            b4 = *reinterpret_cast<const float4*>(xr + NFULL * TILE + lane * EPL + 4);
        }

        float b = S * a.x;
        b = fmaf(S, a.y,  OMS * b);
        b = fmaf(S, a.z,  OMS * b);
        b = fmaf(S, a.w,  OMS * b);
        b = fmaf(S, b4.x, OMS * b);
        b = fmaf(S, b4.y, OMS * b);
        b = fmaf(S, b4.z, OMS * b);
        b = fmaf(S, b4.w, OMS * b);

        float I = b, tv;
        tv = __shfl_up(I, 1);  I = fmaf(K1,  (lane >= 1  ? tv : 0.0f), I);
        tv = __shfl_up(I, 2);  I = fmaf(K2,  (lane >= 2  ? tv : 0.0f), I);
        tv = __shfl_up(I, 4);  I = fmaf(K4,  (lane >= 4  ? tv : 0.0f), I);
        tv = __shfl_up(I, 8);  I = fmaf(K8,  (lane >= 8  ? tv : 0.0f), I);
        tv = __shfl_up(I, 16); I = fmaf(K16, (lane >= 16 ? tv : 0.0f), I);
        tv = __shfl_up(I, 32); I = fmaf(K32, (lane >= 32 ? tv : 0.0f), I);

        float M = fmaf(c, M0, (I - b) * invK);

        float4 oa, ob;
        M = fmaf(S, a.x,  OMS * M);  oa.x = pcen_y(a.x,  M);
        M = fmaf(S, a.y,  OMS * M);  oa.y = pcen_y(a.y,  M);
        M = fmaf(S, a.z,  OMS * M);  oa.z = pcen_y(a.z,  M);
        M = fmaf(S, a.w,  OMS * M);  oa.w = pcen_y(a.w,  M);
        M = fmaf(S, b4.x, OMS * M);  ob.x = pcen_y(b4.x, M);
        M = fmaf(S, b4.y, OMS * M);  ob.y = pcen_y(b4.y, M);
        M = fmaf(S, b4.z, OMS * M);  ob.z = pcen_y(b4.z, M);
        M = fmaf(S, b4.w, OMS * M);  ob.w = pcen_y(b4.w, M);

        if (act) {
            *reinterpret_cast<float4*>(yr + NFULL * TILE + lane * EPL)     = oa;
            *reinterpret_cast<float4*>(yr + NFULL * TILE + lane * EPL + 4) = ob;
        }
    }
}

extern "C" void kernel_launch(void* const* d_in, const int* in_sizes, int n_in,
                              void* d_out, int out_size, void* d_ws, size_t ws_size,
                              hipStream_t stream) {
    const float* x = (const float*)d_in[0];
    float* y       = (float*)d_out;
    pcen_kernel<<<8192 / 4, 256, 0, stream>>>(x, y);  // 2048 blocks, 4 rows each
}